// Round 2
// baseline (3625.897 us; speedup 1.0000x reference)
//
#include <hip/hip_runtime.h>
#include <hip/hip_fp16.h>

// GRU(SEQ=2048, BATCH=64, DIN=128, DH=256) + attention pooling.
//   k_prep_w  : cast W_ih/W_hh -> fp16; fuse b_ih + b_hh(r,z); keep b_hh(n)
//   k_gi      : per seq-chunk: gi16 = mask(data) @ W_ih^T + bias (MFMA f16)
//               A staged once per block (f32 read + mask fused), N-tile loop
//   k_rnn     : per seq-chunk: 64 WGs (1/batch elem), W_hh fp16 register-resident,
//               v_dot2_f32_f16 matvec, f32 hidden state, h carried via ws
//   k_scores  : scores[s][b] = outs16[s][b,:] . w_att
//   k_att     : softmax over s + weighted sum -> d_out (f32 64x256)
// Workspace is adaptive: gi buffer sized to largest chunk CH that fits.

#define SEQ   2048
#define BATCH 64
#define DIN   128
#define DH    256
#define G3    768

typedef _Float16 h2 __attribute__((ext_vector_type(2)));
typedef _Float16 h8 __attribute__((ext_vector_type(8)));
typedef float f32x4 __attribute__((ext_vector_type(4)));

#if __has_builtin(__builtin_amdgcn_fdot2)
__device__ __forceinline__ float fd2(unsigned int a, unsigned int b, float c) {
  return __builtin_amdgcn_fdot2(__builtin_bit_cast(h2, a), __builtin_bit_cast(h2, b), c, false);
}
#else
__device__ __forceinline__ float fd2(unsigned int a, unsigned int b, float c) {
  h2 x = __builtin_bit_cast(h2, a), y = __builtin_bit_cast(h2, b);
  return c + (float)x[0] * (float)y[0] + (float)x[1] * (float)y[1];
}
#endif

// ---------------- prep: weights ----------------
__global__ __launch_bounds__(256) void k_prep_w(const float* __restrict__ wih,
    const float* __restrict__ whh, const float* __restrict__ bih,
    const float* __restrict__ bhh, _Float16* __restrict__ wih16,
    _Float16* __restrict__ whh16, float* __restrict__ biasf,
    float* __restrict__ bhnf) {
  int i = blockIdx.x * 256 + threadIdx.x;
  if (i < 98304) { wih16[i] = (_Float16)wih[i]; return; }
  i -= 98304;
  if (i < 196608) { whh16[i] = (_Float16)whh[i]; return; }
  i -= 196608;
  if (i < 768) { biasf[i] = bih[i] + (i < 512 ? bhh[i] : 0.0f); return; }
  i -= 768;
  if (i < 256) bhnf[i] = bhh[512 + i];
}

// ---------------- gi GEMM over one chunk: rows = CH*64, N=768, K=128 ----------
// A (masked data, f16) staged ONCE per block; loop over 12 N-tiles of W.
#define LDK 136  // padded fp16 leading dim

__global__ __launch_bounds__(256) void k_gi(const float* __restrict__ data,
    const _Float16* __restrict__ w16, const float* __restrict__ bias,
    _Float16* __restrict__ gi16, int s0) {
  __shared__ _Float16 As[128][LDK];
  __shared__ _Float16 Ws[64][LDK];
  int tid = threadIdx.x;
  int m0 = blockIdx.x * 128;                 // chunk-local row
  size_t gm0 = (size_t)s0 * 64 + m0;         // global sb row

  // stage A with mask: 2 threads per row, 64 f32 each -> f16
  {
    int r = tid >> 1, c0 = (tid & 1) * 64;
    const float4* src = (const float4*)(data + (gm0 + r) * DIN + c0);
    float last = data[(gm0 + r) * DIN + 127];
    bool msk = (last > 0.0f) && (c0 == 0);
    #pragma unroll
    for (int i = 0; i < 16; ++i) {
      float4 t = src[i];
      if (msk && i >= 8) t = make_float4(0.f, 0.f, 0.f, 0.f);
      union { _Float16 h[4]; uint2 u; } pk;
      pk.h[0] = (_Float16)t.x; pk.h[1] = (_Float16)t.y;
      pk.h[2] = (_Float16)t.z; pk.h[3] = (_Float16)t.w;
      *(uint2*)&As[r][c0 + i * 4] = pk.u;
    }
  }

  int w = tid >> 6, lane = tid & 63;
  int wm = (w >> 1) * 64, wn = (w & 1) * 32;
  int l16 = lane & 15, lhi = lane >> 4;

  for (int nb = 0; nb < 12; ++nb) {
    // stage W tile: 64 rows x 128 f16 (4 threads per row)
    {
      int r = tid >> 2, cc = (tid & 3) * 32;
      const uint4* src = (const uint4*)(w16 + (size_t)(nb * 64 + r) * DIN + cc);
      #pragma unroll
      for (int i = 0; i < 4; ++i)
        *(uint4*)&Ws[r][cc + i * 8] = src[i];
    }
    __syncthreads();

    f32x4 acc[4][2];
    #pragma unroll
    for (int mi = 0; mi < 4; ++mi)
      #pragma unroll
      for (int ni = 0; ni < 2; ++ni)
        acc[mi][ni] = (f32x4){0.f, 0.f, 0.f, 0.f};

    #pragma unroll
    for (int ks = 0; ks < 4; ++ks) {
      int kk = ks * 32 + lhi * 8;
      h8 a[4], bfr[2];
      #pragma unroll
      for (int mi = 0; mi < 4; ++mi)
        a[mi] = *(const h8*)&As[wm + mi * 16 + l16][kk];
      #pragma unroll
      for (int ni = 0; ni < 2; ++ni)
        bfr[ni] = *(const h8*)&Ws[wn + ni * 16 + l16][kk];
      #pragma unroll
      for (int mi = 0; mi < 4; ++mi)
        #pragma unroll
        for (int ni = 0; ni < 2; ++ni)
          acc[mi][ni] = __builtin_amdgcn_mfma_f32_16x16x32_f16(a[mi], bfr[ni], acc[mi][ni], 0, 0, 0);
    }

    #pragma unroll
    for (int mi = 0; mi < 4; ++mi)
      #pragma unroll
      for (int ni = 0; ni < 2; ++ni) {
        int col = nb * 64 + wn + ni * 16 + l16;
        float bv = bias[col];
        #pragma unroll
        for (int r = 0; r < 4; ++r) {
          int row = m0 + wm + mi * 16 + lhi * 4 + r;
          gi16[(size_t)row * G3 + col] = (_Float16)(acc[mi][ni][r] + bv);
        }
      }
    __syncthreads();  // before next N-tile overwrites Ws
  }
}

// ---------------- recurrent kernel over one chunk ----------------
// thread = (Q in 0..127 owning dims {2Q,2Q+1}, c in 0..3 owning K-chunk of 64)
// weights: 6 rows x 64 fp16 = 192 VGPRs register resident; h f32 in regs,
// fp16x2 in swizzled LDS. h carried between chunk launches via hstate (f32).
__global__ __launch_bounds__(512, 2) void k_rnn(const _Float16* __restrict__ whh16,
    const _Float16* __restrict__ gi16, const float* __restrict__ bhnf,
    _Float16* __restrict__ outs16, float* __restrict__ hstate, int s0, int CH) {
  // logical dword D (f16-pair index 0..127) at phys (D>>5)*36 + (D&31)
  __shared__ __align__(16) unsigned int hsh[2][140];
  int b = blockIdx.x;
  int tid = threadIdx.x;
  int lane = tid & 63;
  int c = lane & 3;
  int Q = (tid >> 6) * 16 + (lane >> 2);  // 0..127
  int j0 = 2 * Q;

  uint4 wv[6][8];
  #pragma unroll
  for (int d = 0; d < 2; ++d)
    #pragma unroll
    for (int g = 0; g < 3; ++g) {
      const uint4* src = (const uint4*)(whh16 + (size_t)(g * 256 + j0 + d) * DH + c * 64);
      #pragma unroll
      for (int i = 0; i < 8; ++i) wv[d * 3 + g][i] = src[i];
    }
  float bn0 = bhnf[j0], bn1 = bhnf[j0 + 1];
  float h0, h1;
  if (s0 == 0) { h0 = 0.f; h1 = 0.f; }
  else { h0 = hstate[b * 256 + j0]; h1 = hstate[b * 256 + j0 + 1]; }

  int wr = (Q >> 5) * 36 + (Q & 31);  // phys write slot for this thread's pair
  if (c == 0) {
    union { _Float16 h[2]; unsigned int u; } pk;
    pk.h[0] = (_Float16)h0; pk.h[1] = (_Float16)h1;
    hsh[0][wr] = pk.u;
  }
  __syncthreads();

  const unsigned int* gi32 = (const unsigned int*)gi16;
  unsigned int* outs32 = (unsigned int*)outs16;
  size_t gbase = (size_t)b * 384 + Q;                       // chunk-local
  size_t obase = ((size_t)s0 * 64 + b) * 128 + Q;           // global
  int p = 0;

  for (int s = 0; s < CH; ++s) {
    unsigned int gr = gi32[gbase];
    unsigned int gz = gi32[gbase + 128];
    unsigned int gn = gi32[gbase + 256];

    const uint4* hp = (const uint4*)&hsh[p][c * 36];
    float a0 = 0.f, a1 = 0.f, a2 = 0.f, a3 = 0.f, a4 = 0.f, a5 = 0.f;
    #pragma unroll
    for (int u = 0; u < 8; ++u) {
      uint4 hv = hp[u];
      uint4 w0 = wv[0][u], w1 = wv[1][u], w2 = wv[2][u];
      uint4 w3 = wv[3][u], w4 = wv[4][u], w5 = wv[5][u];
      a0 = fd2(w0.x, hv.x, a0); a0 = fd2(w0.y, hv.y, a0); a0 = fd2(w0.z, hv.z, a0); a0 = fd2(w0.w, hv.w, a0);
      a1 = fd2(w1.x, hv.x, a1); a1 = fd2(w1.y, hv.y, a1); a1 = fd2(w1.z, hv.z, a1); a1 = fd2(w1.w, hv.w, a1);
      a2 = fd2(w2.x, hv.x, a2); a2 = fd2(w2.y, hv.y, a2); a2 = fd2(w2.z, hv.z, a2); a2 = fd2(w2.w, hv.w, a2);
      a3 = fd2(w3.x, hv.x, a3); a3 = fd2(w3.y, hv.y, a3); a3 = fd2(w3.z, hv.z, a3); a3 = fd2(w3.w, hv.w, a3);
      a4 = fd2(w4.x, hv.x, a4); a4 = fd2(w4.y, hv.y, a4); a4 = fd2(w4.z, hv.z, a4); a4 = fd2(w4.w, hv.w, a4);
      a5 = fd2(w5.x, hv.x, a5); a5 = fd2(w5.y, hv.y, a5); a5 = fd2(w5.z, hv.z, a5); a5 = fd2(w5.w, hv.w, a5);
    }
    a0 += __shfl_xor(a0, 1); a0 += __shfl_xor(a0, 2);
    a1 += __shfl_xor(a1, 1); a1 += __shfl_xor(a1, 2);
    a2 += __shfl_xor(a2, 1); a2 += __shfl_xor(a2, 2);
    a3 += __shfl_xor(a3, 1); a3 += __shfl_xor(a3, 2);
    a4 += __shfl_xor(a4, 1); a4 += __shfl_xor(a4, 2);
    a5 += __shfl_xor(a5, 1); a5 += __shfl_xor(a5, 2);

    h2 grh = __builtin_bit_cast(h2, gr);
    h2 gzh = __builtin_bit_cast(h2, gz);
    h2 gnh = __builtin_bit_cast(h2, gn);
    {
      float r = 1.f / (1.f + __expf(-((float)grh[0] + a0)));
      float z = 1.f / (1.f + __expf(-((float)gzh[0] + a1)));
      float x = (float)gnh[0] + r * (a2 + bn0);
      float n = 1.f - 2.f / (__expf(2.f * x) + 1.f);
      h0 = n + z * (h0 - n);
    }
    {
      float r = 1.f / (1.f + __expf(-((float)grh[1] + a3)));
      float z = 1.f / (1.f + __expf(-((float)gzh[1] + a4)));
      float x = (float)gnh[1] + r * (a5 + bn1);
      float n = 1.f - 2.f / (__expf(2.f * x) + 1.f);
      h1 = n + z * (h1 - n);
    }
    union { _Float16 h[2]; unsigned int u; } pk;
    pk.h[0] = (_Float16)h0; pk.h[1] = (_Float16)h1;
    if (c == 0) {
      hsh[p ^ 1][wr] = pk.u;
      outs32[obase] = pk.u;
    }
    __syncthreads();
    p ^= 1;
    gbase += 64 * 384;
    obase += 64 * 128;
  }

  if (c == 0) {
    hstate[b * 256 + j0] = h0;
    hstate[b * 256 + j0 + 1] = h1;
  }
}

// ---------------- attention: scores ----------------
__global__ __launch_bounds__(256) void k_scores(const _Float16* __restrict__ outs16,
    const float* __restrict__ watt, float* __restrict__ scores) {
  int idx = blockIdx.x * 4 + (threadIdx.x >> 6);  // sb index
  int lane = threadIdx.x & 63;
  const uint2* row = (const uint2*)((const unsigned int*)outs16 + (size_t)idx * 128 + lane * 2);
  uint2 v = *row;
  float4 w = *(const float4*)(watt + lane * 4);
  h2 va = __builtin_bit_cast(h2, v.x);
  h2 vb = __builtin_bit_cast(h2, v.y);
  float sum = (float)va[0] * w.x + (float)va[1] * w.y + (float)vb[0] * w.z + (float)vb[1] * w.w;
  #pragma unroll
  for (int m = 1; m < 64; m <<= 1) sum += __shfl_xor(sum, m);
  if (lane == 0) scores[idx] = sum;
}

// ---------------- attention: softmax + weighted sum ----------------
__global__ __launch_bounds__(256) void k_att(const _Float16* __restrict__ outs16,
    const float* __restrict__ scores, float* __restrict__ out) {
  __shared__ float al[SEQ];
  __shared__ float red[12];
  int b = blockIdx.x, t = threadIdx.x;
  float v[8];
  float m = -1e30f;
  #pragma unroll
  for (int i = 0; i < 8; ++i) {
    v[i] = scores[(size_t)(t + i * 256) * 64 + b];
    m = fmaxf(m, v[i]);
  }
  #pragma unroll
  for (int k = 1; k < 64; k <<= 1) m = fmaxf(m, __shfl_xor(m, k));
  if ((t & 63) == 0) red[t >> 6] = m;
  __syncthreads();
  m = fmaxf(fmaxf(red[0], red[1]), fmaxf(red[2], red[3]));
  float l = 0.f;
  #pragma unroll
  for (int i = 0; i < 8; ++i) {
    float e = __expf(v[i] - m);
    al[t + i * 256] = e;
    l += e;
  }
  #pragma unroll
  for (int k = 1; k < 64; k <<= 1) l += __shfl_xor(l, k);
  if ((t & 63) == 0) red[8 + (t >> 6)] = l;
  __syncthreads();
  l = red[8] + red[9] + red[10] + red[11];
  float inv = 1.f / l;

  float acc = 0.f;
  const unsigned int* o32 = (const unsigned int*)outs16;
  size_t base = (size_t)b * 128 + (t >> 1);
  int hi = t & 1;
  for (int s = 0; s < SEQ; ++s) {
    unsigned int u = o32[base + (size_t)s * 8192];
    h2 hh = __builtin_bit_cast(h2, u);
    acc += al[s] * (float)hh[hi];
  }
  out[b * 256 + t] = acc * inv;
}

__global__ __launch_bounds__(256) void k_fill(float* out, float v, int n) {
  int i = blockIdx.x * 256 + threadIdx.x;
  if (i < n) out[i] = v;
}

// ---------------- launch ----------------
extern "C" void kernel_launch(void* const* d_in, const int* in_sizes, int n_in,
                              void* d_out, int out_size, void* d_ws, size_t ws_size,
                              hipStream_t stream) {
  const float* data = (const float*)d_in[0];
  const float* wih  = (const float*)d_in[1];
  const float* whh  = (const float*)d_in[2];
  const float* bih  = (const float*)d_in[3];
  const float* bhh  = (const float*)d_in[4];
  const float* watt = (const float*)d_in[5];
  float* out = (float*)d_out;

  // fixed-layout workspace; gi chunk buffer last, sized adaptively
  const size_t OFF_WIH    = 0;           //    196,608
  const size_t OFF_WHH    = 196608;      //    393,216
  const size_t OFF_BIAS   = 589824;      //      3,072
  const size_t OFF_BHN    = 592896;      //      1,024
  const size_t OFF_H      = 593920;      //     65,536
  const size_t OFF_SCORES = 659456;      //    524,288
  const size_t OFF_OUTS   = 1183744;     // 67,108,864
  const size_t OFF_GI     = 68292608;

  int CH = 0;
  for (int ch = SEQ; ch >= 64; ch >>= 1) {
    if (OFF_GI + (size_t)ch * 64 * G3 * 2 <= ws_size) { CH = ch; break; }
  }
  if (CH == 0) {
    k_fill<<<(out_size + 255) / 256, 256, 0, stream>>>(out, 2.0e6f, out_size);
    return;
  }

  char* ws = (char*)d_ws;
  _Float16* wih16  = (_Float16*)(ws + OFF_WIH);
  _Float16* whh16  = (_Float16*)(ws + OFF_WHH);
  float*    biasf  = (float*)(ws + OFF_BIAS);
  float*    bhnf   = (float*)(ws + OFF_BHN);
  float*    hstate = (float*)(ws + OFF_H);
  float*    scores = (float*)(ws + OFF_SCORES);
  _Float16* outs16 = (_Float16*)(ws + OFF_OUTS);
  _Float16* gi16   = (_Float16*)(ws + OFF_GI);

  k_prep_w<<<(98304 + 196608 + 768 + 256 + 255) / 256, 256, 0, stream>>>(
      wih, whh, bih, bhh, wih16, whh16, biasf, bhnf);

  for (int s0 = 0; s0 < SEQ; s0 += CH) {
    k_gi<<<CH * 64 / 128, 256, 0, stream>>>(data, wih16, biasf, gi16, s0);
    k_rnn<<<BATCH, 512, 0, stream>>>(whh16, gi16, bhnf, outs16, hstate, s0, CH);
  }

  k_scores<<<SEQ * BATCH / 4, 256, 0, stream>>>(outs16, watt, scores);
  k_att<<<BATCH, 256, 0, stream>>>(outs16, scores, out);
}

// Round 4
// 3524.785 us; speedup vs baseline: 1.0287x; 1.0287x over previous
//
#include <hip/hip_runtime.h>
#include <hip/hip_fp16.h>

// GRU(SEQ=2048, BATCH=64, DIN=128, DH=256) + attention pooling.
//   k_prep_w  : cast W_ih/W_hh -> fp16; fuse b_ih + b_hh(r,z); keep b_hh(n)
//   k_gi      : per seq-chunk: gi16 = mask(data) @ W_ih^T + bias (MFMA f16)
//   k_rnn     : per seq-chunk: 64 WGs (1/batch elem), W_hh fp16 PINNED in VGPRs
//               (asm "+v" anti-remat), v_dot2_f32_f16 matvec, DPP quad reduce,
//               f32 hidden state, h carried across chunks via ws
//   k_scores  : scores[s][b] = outs16[s][b,:] . w_att
//   k_att     : softmax over s + weighted sum -> d_out (f32 64x256)

#define SEQ   2048
#define BATCH 64
#define DIN   128
#define DH    256
#define G3    768

typedef _Float16 h2 __attribute__((ext_vector_type(2)));
typedef _Float16 h8 __attribute__((ext_vector_type(8)));
typedef float f32x4 __attribute__((ext_vector_type(4)));

#if __has_builtin(__builtin_amdgcn_fdot2)
__device__ __forceinline__ float fd2(unsigned int a, unsigned int b, float c) {
  return __builtin_amdgcn_fdot2(__builtin_bit_cast(h2, a), __builtin_bit_cast(h2, b), c, false);
}
#else
__device__ __forceinline__ float fd2(unsigned int a, unsigned int b, float c) {
  h2 x = __builtin_bit_cast(h2, a), y = __builtin_bit_cast(h2, b);
  return c + (float)x[0] * (float)y[0] + (float)x[1] * (float)y[1];
}
#endif

// quad-perm butterfly add: after <0xB1> then <0x4E>, all 4 lanes of each quad
// hold the 4-lane sum. Pure VALU (no LDS pipe).
template <int CTRL>
__device__ __forceinline__ float dppadd(float x) {
  int t = __builtin_amdgcn_mov_dpp(__builtin_bit_cast(int, x), CTRL, 0xF, 0xF, true);
  return x + __builtin_bit_cast(float, t);
}

// ---------------- prep: weights ----------------
__global__ __launch_bounds__(256) void k_prep_w(const float* __restrict__ wih,
    const float* __restrict__ whh, const float* __restrict__ bih,
    const float* __restrict__ bhh, _Float16* __restrict__ wih16,
    _Float16* __restrict__ whh16, float* __restrict__ biasf,
    float* __restrict__ bhnf) {
  int i = blockIdx.x * 256 + threadIdx.x;
  if (i < 98304) { wih16[i] = (_Float16)wih[i]; return; }
  i -= 98304;
  if (i < 196608) { whh16[i] = (_Float16)whh[i]; return; }
  i -= 196608;
  if (i < 768) { biasf[i] = bih[i] + (i < 512 ? bhh[i] : 0.0f); return; }
  i -= 768;
  if (i < 256) bhnf[i] = bhh[512 + i];
}

// ---------------- gi GEMM over one chunk: rows = CH*64, N=768, K=128 ----------
#define LDK 136  // padded fp16 leading dim

__global__ __launch_bounds__(256) void k_gi(const float* __restrict__ data,
    const _Float16* __restrict__ w16, const float* __restrict__ bias,
    _Float16* __restrict__ gi16, int s0) {
  __shared__ _Float16 As[128][LDK];
  __shared__ _Float16 Ws[64][LDK];
  int tid = threadIdx.x;
  int m0 = blockIdx.x * 128;                 // chunk-local row
  size_t gm0 = (size_t)s0 * 64 + m0;         // global sb row

  // stage A with mask: 2 threads per row, 64 f32 each -> f16
  {
    int r = tid >> 1, c0 = (tid & 1) * 64;
    const float4* src = (const float4*)(data + (gm0 + r) * DIN + c0);
    float last = data[(gm0 + r) * DIN + 127];
    bool msk = (last > 0.0f) && (c0 == 0);
    #pragma unroll
    for (int i = 0; i < 16; ++i) {
      float4 t = src[i];
      if (msk && i >= 8) t = make_float4(0.f, 0.f, 0.f, 0.f);
      union { _Float16 h[4]; uint2 u; } pk;
      pk.h[0] = (_Float16)t.x; pk.h[1] = (_Float16)t.y;
      pk.h[2] = (_Float16)t.z; pk.h[3] = (_Float16)t.w;
      *(uint2*)&As[r][c0 + i * 4] = pk.u;
    }
  }

  int w = tid >> 6, lane = tid & 63;
  int wm = (w >> 1) * 64, wn = (w & 1) * 32;
  int l16 = lane & 15, lhi = lane >> 4;

  for (int nb = 0; nb < 12; ++nb) {
    {
      int r = tid >> 2, cc = (tid & 3) * 32;
      const uint4* src = (const uint4*)(w16 + (size_t)(nb * 64 + r) * DIN + cc);
      #pragma unroll
      for (int i = 0; i < 4; ++i)
        *(uint4*)&Ws[r][cc + i * 8] = src[i];
    }
    __syncthreads();

    f32x4 acc[4][2];
    #pragma unroll
    for (int mi = 0; mi < 4; ++mi)
      #pragma unroll
      for (int ni = 0; ni < 2; ++ni)
        acc[mi][ni] = (f32x4){0.f, 0.f, 0.f, 0.f};

    #pragma unroll
    for (int ks = 0; ks < 4; ++ks) {
      int kk = ks * 32 + lhi * 8;
      h8 a[4], bfr[2];
      #pragma unroll
      for (int mi = 0; mi < 4; ++mi)
        a[mi] = *(const h8*)&As[wm + mi * 16 + l16][kk];
      #pragma unroll
      for (int ni = 0; ni < 2; ++ni)
        bfr[ni] = *(const h8*)&Ws[wn + ni * 16 + l16][kk];
      #pragma unroll
      for (int mi = 0; mi < 4; ++mi)
        #pragma unroll
        for (int ni = 0; ni < 2; ++ni)
          acc[mi][ni] = __builtin_amdgcn_mfma_f32_16x16x32_f16(a[mi], bfr[ni], acc[mi][ni], 0, 0, 0);
    }

    #pragma unroll
    for (int mi = 0; mi < 4; ++mi)
      #pragma unroll
      for (int ni = 0; ni < 2; ++ni) {
        int col = nb * 64 + wn + ni * 16 + l16;
        float bv = bias[col];
        #pragma unroll
        for (int r = 0; r < 4; ++r) {
          int row = m0 + wm + mi * 16 + lhi * 4 + r;
          gi16[(size_t)row * G3 + col] = (_Float16)(acc[mi][ni][r] + bv);
        }
      }
    __syncthreads();
  }
}

// ---------------- recurrent kernel over one chunk ----------------
// thread = (Q in 0..127 owning dims {2Q,2Q+1}, c in 0..3 owning K-chunk of 64)
// weights: 6 rows x 64 fp16 = 192 VGPRs, pinned via asm; h f32 in regs,
// fp16x2 in swizzled LDS. h carried between chunk launches via hstate (f32).
__global__ __launch_bounds__(512, 2) void k_rnn(const _Float16* __restrict__ whh16,
    const _Float16* __restrict__ gi16, const float* __restrict__ bhnf,
    _Float16* __restrict__ outs16, float* __restrict__ hstate, int s0, int CH) {
  // logical dword D (f16-pair index 0..127) at phys (D>>5)*36 + (D&31)
  __shared__ __align__(16) unsigned int hsh[2][140];
  int b = blockIdx.x;
  int tid = threadIdx.x;
  int lane = tid & 63;
  int c = lane & 3;
  int Q = (tid >> 6) * 16 + (lane >> 2);  // 0..127
  int j0 = 2 * Q;

  uint4 wv[6][8];
  #pragma unroll
  for (int d = 0; d < 2; ++d)
    #pragma unroll
    for (int g = 0; g < 3; ++g) {
      const uint4* src = (const uint4*)(whh16 + (size_t)(g * 256 + j0 + d) * DH + c * 64);
      #pragma unroll
      for (int i = 0; i < 8; ++i) wv[d * 3 + g][i] = src[i];
    }
  // PIN: opaque redefinition — compiler cannot rematerialize these from memory,
  // so all 192 dwords must stay resident in VGPRs across the step loop.
  #pragma unroll
  for (int g = 0; g < 6; ++g)
    #pragma unroll
    for (int i = 0; i < 8; ++i)
      asm volatile("" : "+v"(wv[g][i].x), "+v"(wv[g][i].y),
                        "+v"(wv[g][i].z), "+v"(wv[g][i].w));

  float bn0 = bhnf[j0], bn1 = bhnf[j0 + 1];
  float h0, h1;
  if (s0 == 0) { h0 = 0.f; h1 = 0.f; }
  else { h0 = hstate[b * 256 + j0]; h1 = hstate[b * 256 + j0 + 1]; }

  int wr = (Q >> 5) * 36 + (Q & 31);  // phys write slot for this thread's pair
  if (c == 0) {
    union { _Float16 h[2]; unsigned int u; } pk;
    pk.h[0] = (_Float16)h0; pk.h[1] = (_Float16)h1;
    hsh[0][wr] = pk.u;
  }
  __syncthreads();

  const unsigned int* gi32 = (const unsigned int*)gi16;
  unsigned int* outs32 = (unsigned int*)outs16;
  size_t gbase = (size_t)b * 384 + Q;                       // chunk-local
  size_t obase = ((size_t)s0 * 64 + b) * 128 + Q;           // global
  int p = 0;

  for (int s = 0; s < CH; ++s) {
    unsigned int gr = gi32[gbase];
    unsigned int gz = gi32[gbase + 128];
    unsigned int gn = gi32[gbase + 256];

    const uint4* hp = (const uint4*)&hsh[p][c * 36];
    float a0 = 0.f, a1 = 0.f, a2 = 0.f, a3 = 0.f, a4 = 0.f, a5 = 0.f;
    #pragma unroll
    for (int u = 0; u < 8; ++u) {
      uint4 hv = hp[u];
      a0 = fd2(wv[0][u].x, hv.x, a0); a0 = fd2(wv[0][u].y, hv.y, a0);
      a0 = fd2(wv[0][u].z, hv.z, a0); a0 = fd2(wv[0][u].w, hv.w, a0);
      a1 = fd2(wv[1][u].x, hv.x, a1); a1 = fd2(wv[1][u].y, hv.y, a1);
      a1 = fd2(wv[1][u].z, hv.z, a1); a1 = fd2(wv[1][u].w, hv.w, a1);
      a2 = fd2(wv[2][u].x, hv.x, a2); a2 = fd2(wv[2][u].y, hv.y, a2);
      a2 = fd2(wv[2][u].z, hv.z, a2); a2 = fd2(wv[2][u].w, hv.w, a2);
      a3 = fd2(wv[3][u].x, hv.x, a3); a3 = fd2(wv[3][u].y, hv.y, a3);
      a3 = fd2(wv[3][u].z, hv.z, a3); a3 = fd2(wv[3][u].w, hv.w, a3);
      a4 = fd2(wv[4][u].x, hv.x, a4); a4 = fd2(wv[4][u].y, hv.y, a4);
      a4 = fd2(wv[4][u].z, hv.z, a4); a4 = fd2(wv[4][u].w, hv.w, a4);
      a5 = fd2(wv[5][u].x, hv.x, a5); a5 = fd2(wv[5][u].y, hv.y, a5);
      a5 = fd2(wv[5][u].z, hv.z, a5); a5 = fd2(wv[5][u].w, hv.w, a5);
    }
    // 4-lane butterfly via DPP quad_perm (pure VALU, sum lands in all 4 lanes)
    a0 = dppadd<0xB1>(a0); a0 = dppadd<0x4E>(a0);
    a1 = dppadd<0xB1>(a1); a1 = dppadd<0x4E>(a1);
    a2 = dppadd<0xB1>(a2); a2 = dppadd<0x4E>(a2);
    a3 = dppadd<0xB1>(a3); a3 = dppadd<0x4E>(a3);
    a4 = dppadd<0xB1>(a4); a4 = dppadd<0x4E>(a4);
    a5 = dppadd<0xB1>(a5); a5 = dppadd<0x4E>(a5);

    h2 grh = __builtin_bit_cast(h2, gr);
    h2 gzh = __builtin_bit_cast(h2, gz);
    h2 gnh = __builtin_bit_cast(h2, gn);
    {
      float r = 1.f / (1.f + __expf(-((float)grh[0] + a0)));
      float z = 1.f / (1.f + __expf(-((float)gzh[0] + a1)));
      float x = (float)gnh[0] + r * (a2 + bn0);
      float n = 1.f - 2.f / (__expf(2.f * x) + 1.f);
      h0 = n + z * (h0 - n);
    }
    {
      float r = 1.f / (1.f + __expf(-((float)grh[1] + a3)));
      float z = 1.f / (1.f + __expf(-((float)gzh[1] + a4)));
      float x = (float)gnh[1] + r * (a5 + bn1);
      float n = 1.f - 2.f / (__expf(2.f * x) + 1.f);
      h1 = n + z * (h1 - n);
    }
    union { _Float16 h[2]; unsigned int u; } pk;
    pk.h[0] = (_Float16)h0; pk.h[1] = (_Float16)h1;
    if (c == 0) {
      hsh[p ^ 1][wr] = pk.u;
      outs32[obase] = pk.u;
    }
    __syncthreads();
    p ^= 1;
    gbase += 64 * 384;
    obase += 64 * 128;
  }

  if (c == 0) {
    hstate[b * 256 + j0] = h0;
    hstate[b * 256 + j0 + 1] = h1;
  }
}

// ---------------- attention: scores ----------------
__global__ __launch_bounds__(256) void k_scores(const _Float16* __restrict__ outs16,
    const float* __restrict__ watt, float* __restrict__ scores) {
  int idx = blockIdx.x * 4 + (threadIdx.x >> 6);  // sb index
  int lane = threadIdx.x & 63;
  const uint2* row = (const uint2*)((const unsigned int*)outs16 + (size_t)idx * 128 + lane * 2);
  uint2 v = *row;
  float4 w = *(const float4*)(watt + lane * 4);
  h2 va = __builtin_bit_cast(h2, v.x);
  h2 vb = __builtin_bit_cast(h2, v.y);
  float sum = (float)va[0] * w.x + (float)va[1] * w.y + (float)vb[0] * w.z + (float)vb[1] * w.w;
  #pragma unroll
  for (int m = 1; m < 64; m <<= 1) sum += __shfl_xor(sum, m);
  if (lane == 0) scores[idx] = sum;
}

// ---------------- attention: softmax + weighted sum ----------------
__global__ __launch_bounds__(256) void k_att(const _Float16* __restrict__ outs16,
    const float* __restrict__ scores, float* __restrict__ out) {
  __shared__ float al[SEQ];
  __shared__ float red[12];
  int b = blockIdx.x, t = threadIdx.x;
  float v[8];
  float m = -1e30f;
  #pragma unroll
  for (int i = 0; i < 8; ++i) {
    v[i] = scores[(size_t)(t + i * 256) * 64 + b];
    m = fmaxf(m, v[i]);
  }
  #pragma unroll
  for (int k = 1; k < 64; k <<= 1) m = fmaxf(m, __shfl_xor(m, k));
  if ((t & 63) == 0) red[t >> 6] = m;
  __syncthreads();
  m = fmaxf(fmaxf(red[0], red[1]), fmaxf(red[2], red[3]));
  float l = 0.f;
  #pragma unroll
  for (int i = 0; i < 8; ++i) {
    float e = __expf(v[i] - m);
    al[t + i * 256] = e;
    l += e;
  }
  #pragma unroll
  for (int k = 1; k < 64; k <<= 1) l += __shfl_xor(l, k);
  if ((t & 63) == 0) red[8 + (t >> 6)] = l;
  __syncthreads();
  l = red[8] + red[9] + red[10] + red[11];
  float inv = 1.f / l;

  float acc = 0.f;
  const unsigned int* o32 = (const unsigned int*)outs16;
  size_t base = (size_t)b * 128 + (t >> 1);
  int hi = t & 1;
  for (int s = 0; s < SEQ; ++s) {
    unsigned int u = o32[base + (size_t)s * 8192];
    h2 hh = __builtin_bit_cast(h2, u);
    acc += al[s] * (float)hh[hi];
  }
  out[b * 256 + t] = acc * inv;
}

__global__ __launch_bounds__(256) void k_fill(float* out, float v, int n) {
  int i = blockIdx.x * 256 + threadIdx.x;
  if (i < n) out[i] = v;
}

// ---------------- launch ----------------
extern "C" void kernel_launch(void* const* d_in, const int* in_sizes, int n_in,
                              void* d_out, int out_size, void* d_ws, size_t ws_size,
                              hipStream_t stream) {
  const float* data = (const float*)d_in[0];
  const float* wih  = (const float*)d_in[1];
  const float* whh  = (const float*)d_in[2];
  const float* bih  = (const float*)d_in[3];
  const float* bhh  = (const float*)d_in[4];
  const float* watt = (const float*)d_in[5];
  float* out = (float*)d_out;

  const size_t OFF_WIH    = 0;           //    196,608
  const size_t OFF_WHH    = 196608;      //    393,216
  const size_t OFF_BIAS   = 589824;      //      3,072
  const size_t OFF_BHN    = 592896;      //      1,024
  const size_t OFF_H      = 593920;      //     65,536
  const size_t OFF_SCORES = 659456;      //    524,288
  const size_t OFF_OUTS   = 1183744;     // 67,108,864
  const size_t OFF_GI     = 68292608;

  int CH = 0;
  for (int ch = SEQ; ch >= 64; ch >>= 1) {
    if (OFF_GI + (size_t)ch * 64 * G3 * 2 <= ws_size) { CH = ch; break; }
  }
  if (CH == 0) {
    k_fill<<<(out_size + 255) / 256, 256, 0, stream>>>(out, 2.0e6f, out_size);
    return;
  }

  char* ws = (char*)d_ws;
  _Float16* wih16  = (_Float16*)(ws + OFF_WIH);
  _Float16* whh16  = (_Float16*)(ws + OFF_WHH);
  float*    biasf  = (float*)(ws + OFF_BIAS);
  float*    bhnf   = (float*)(ws + OFF_BHN);
  float*    hstate = (float*)(ws + OFF_H);
  float*    scores = (float*)(ws + OFF_SCORES);
  _Float16* outs16 = (_Float16*)(ws + OFF_OUTS);
  _Float16* gi16   = (_Float16*)(ws + OFF_GI);

  k_prep_w<<<(98304 + 196608 + 768 + 256 + 255) / 256, 256, 0, stream>>>(
      wih, whh, bih, bhh, wih16, whh16, biasf, bhnf);

  for (int s0 = 0; s0 < SEQ; s0 += CH) {
    k_gi<<<CH * 64 / 128, 256, 0, stream>>>(data, wih16, biasf, gi16, s0);
    k_rnn<<<BATCH, 512, 0, stream>>>(whh16, gi16, bhnf, outs16, hstate, s0, CH);
  }

  k_scores<<<SEQ * BATCH / 4, 256, 0, stream>>>(outs16, watt, scores);
  k_att<<<BATCH, 256, 0, stream>>>(outs16, scores, out);
}